// Round 11
// baseline (270.698 us; speedup 1.0000x reference)
//
#include <hip/hip_runtime.h>
#include <math.h>

// GoBERT: GATConv(4x32) -> BN -> GCNConv(128) -> BN -> GlobalAttention -> FC
// Round 10: LDS-free MFMA GEMMs. A-rows are wave-private (no reuse) and B is
// block-shared, so staging both through 68KB LDS only capped occupancy at
// 2 blocks/CU and serialized each block (45.7us at 1.2% MfmaUtil). Now:
// W pre-transposed into MFMA fragment order (k_front) -> coalesced register
// loads; A direct global->register; elu/BN1 transform moved to gat_aggr
// epilogue. Zero LDS / zero barriers in GEMM.

#define NEG_SLOPE 0.2f
#define BKT_BITS 7
#define BKT_SIZE 128
#define CHUNK_A 4096

typedef __attribute__((ext_vector_type(8))) short short8v;
typedef __attribute__((ext_vector_type(4))) float floatx4;

__device__ __forceinline__ int lower_bound_i(const int* a, int n, int key) {
    int lo = 0, hi = n;
    while (lo < hi) {
        int mid = (lo + hi) >> 1;
        if (a[mid] < key) lo = mid + 1; else hi = mid;
    }
    return lo;
}

__device__ __forceinline__ unsigned pack_bf16(float lo, float hi) {
    unsigned ua = __float_as_uint(lo);
    unsigned ub = __float_as_uint(hi);
    ua = ua + 0x7fffu + ((ua >> 16) & 1u);
    ub = ub + 0x7fffu + ((ub >> 16) & 1u);
    return (ua >> 16) | (ub & 0xffff0000u);
}

__device__ __forceinline__ unsigned short bf16_1(float v) {
    unsigned u = __float_as_uint(v);
    u = u + 0x7fffu + ((u >> 16) & 1u);
    return (unsigned short)(u >> 16);
}

// ---------------- front: fragment-ordered weights + bucket hist ------------
// Wf[(ct*4+ks)*512 + lane*8 + j] = W^T[col=ct*16+(lane&15)][k=ks*32+(lane>>4)*8+j]
// Wf1: ct 0-7 = W_gat cols; ct 8: l16<4 -> W@att_src head l16, l16 4-7 ->
// W@att_dst head l16-4, else 0.  Wf2: ct 0-7 = W_gcn cols.
__global__ __launch_bounds__(256) void k_front(
    const float* __restrict__ W1, const float* __restrict__ atts,
    const float* __restrict__ attd, const float* __restrict__ W2,
    unsigned short* __restrict__ Wf1, unsigned short* __restrict__ Wf2,
    const int* __restrict__ dst, int* __restrict__ bcount, int E, int NB)
{
    const int b = blockIdx.x;
    if (b < 2) {
        const int NCT = b ? 8 : 9;
        const float* W = b ? W2 : W1;
        unsigned short* Wf = b ? Wf2 : Wf1;
        const int lim = NCT * 4 * 64 * 8;
        for (int idx = threadIdx.x; idx < lim; idx += 256) {
            int j = idx & 7;
            int lane = (idx >> 3) & 63;
            int frag = idx >> 9;            // ct*4 + ks
            int ct = frag >> 2, ks = frag & 3;
            int quad = lane >> 4, l16 = lane & 15;
            int k = ks * 32 + quad * 8 + j;
            float v;
            if (ct < 8) {
                v = W[k * 128 + ct * 16 + l16];
            } else if (l16 < 4) {
                float s = 0.f;
                for (int c = 0; c < 32; c++) s += W1[k * 128 + l16 * 32 + c] * atts[l16 * 32 + c];
                v = s;
            } else if (l16 < 8) {
                int h = l16 - 4;
                float s = 0.f;
                for (int c = 0; c < 32; c++) s += W1[k * 128 + h * 32 + c] * attd[h * 32 + c];
                v = s;
            } else v = 0.f;
            Wf[idx] = bf16_1(v);
        }
    } else {
        __shared__ int h[512];
        const int tid = threadIdx.x;
        for (int i = tid; i < 512; i += 256) h[i] = 0;
        __syncthreads();
        int base = (b - 2) * 2048;
#pragma unroll
        for (int k = 0; k < 8; k++) {
            int e = base + k * 256 + tid;
            if (e < E) atomicAdd(&h[dst[e] >> BKT_BITS], 1);
        }
        __syncthreads();
        for (int i = tid; i < NB; i += 256) {
            int c = h[i];
            if (c) atomicAdd(&bcount[i], c);
        }
    }
}

// ---------------- LDS-free MFMA GEMM: 64 rows/block (16 rows/wave) ---------
// MODE 0: fp32 A (x), NCT=9, epilogue writes hb + aS/aD from ct=8.
// MODE 1: bf16 A (pre-transformed raw1b), NCT=8, epilogue scales by dinv.
template<int MODE>
__global__ __launch_bounds__(256) void k_gemm_mfma(
    const void* __restrict__ Ain, const unsigned short* __restrict__ Wf,
    unsigned* __restrict__ Cb, int N,
    const float* __restrict__ dinv,
    float* __restrict__ aS, float* __restrict__ aD)
{
    constexpr int NCT = (MODE == 0) ? 9 : 8;
    const int tid = threadIdx.x;
    const int wv = tid >> 6, lane = tid & 63;
    const int quad = lane >> 4, l16 = lane & 15;
    const int n0 = blockIdx.x * 64;
    const int arow = n0 + wv * 16 + l16;        // this lane's A row
    const bool rowok = arow < N;

    floatx4 acc[NCT];
#pragma unroll
    for (int ct = 0; ct < NCT; ct++) acc[ct] = (floatx4){0.f, 0.f, 0.f, 0.f};

    union AV { unsigned u[4]; short8v v; };

#pragma unroll
    for (int ks = 0; ks < 4; ks++) {
        AV a;
        a.u[0] = a.u[1] = a.u[2] = a.u[3] = 0u;
        if (rowok) {
            if (MODE == 0) {
                const float* A = (const float*)Ain;
                const float* p = A + (size_t)arow * 128 + ks * 32 + quad * 8;
                float4 va = *(const float4*)(p);
                float4 vb = *(const float4*)(p + 4);
                a.u[0] = pack_bf16(va.x, va.y);
                a.u[1] = pack_bf16(va.z, va.w);
                a.u[2] = pack_bf16(vb.x, vb.y);
                a.u[3] = pack_bf16(vb.z, vb.w);
            } else {
                const unsigned short* A = (const unsigned short*)Ain;
                a.v = *(const short8v*)(A + (size_t)arow * 128 + ks * 32 + quad * 8);
            }
        }
#pragma unroll
        for (int ct = 0; ct < NCT; ct++) {
            short8v bv = *(const short8v*)(Wf + ((ct * 4 + ks) << 9) + lane * 8);
            acc[ct] = __builtin_amdgcn_mfma_f32_16x16x32_bf16(a.v, bv, acc[ct], 0, 0, 0);
        }
    }

    // epilogue: lane holds D rows quad*4+r, col ct*16+l16
#pragma unroll
    for (int r = 0; r < 4; r++) {
        int n = n0 + wv * 16 + quad * 4 + r;
        if (n >= N) continue;
        float s = MODE ? dinv[n] : 1.f;
#pragma unroll
        for (int ct = 0; ct < 4; ct++) {
            Cb[(size_t)n * 64 + ct * 16 + l16] =
                pack_bf16(acc[ct][r] * s, acc[ct + 4][r] * s);
        }
        if (MODE == 0) {
            float e = acc[8][r];
            if (l16 < 4) aS[(size_t)n * 4 + l16] = e;
            else if (l16 < 8) aD[(size_t)n * 4 + (l16 - 4)] = e;
        }
    }
}

// ---------------- CSR build ----------------
__global__ __launch_bounds__(512) void k_bscan(const int* __restrict__ bcount,
                                               int* __restrict__ bb,
                                               int* __restrict__ bcur, int NB)
{
    __shared__ int sc[512];
    const int tid = threadIdx.x;
    int own = (tid < NB) ? bcount[tid] : 0;
    sc[tid] = own;
    __syncthreads();
    for (int st = 1; st < 512; st <<= 1) {
        int v = 0;
        if (tid >= st) v = sc[tid - st];
        __syncthreads();
        if (tid >= st) sc[tid] += v;
        __syncthreads();
    }
    int excl = sc[tid] - own;
    if (tid < NB) { bb[tid] = excl; bcur[tid] = excl; }
    if (tid == 511) { bb[NB] = sc[511]; bcur[NB] = sc[511]; }
}

__global__ __launch_bounds__(256) void k_binA(const int* __restrict__ ei,
                                              int* __restrict__ bcur,
                                              int2* __restrict__ pairs,
                                              int E, int NB)
{
    __shared__ int h[512];
    __shared__ int base[512];
    const int tid = threadIdx.x;
    for (int i = tid; i < NB + 1; i += 256) h[i] = 0;
    __syncthreads();
    const int c0 = blockIdx.x * CHUNK_A;
    int s[16], d[16], b[16];
#pragma unroll
    for (int k = 0; k < 16; k++) {
        int e = c0 + k * 256 + tid;
        bool v = e < E;
        s[k] = v ? ei[e] : 0;
        d[k] = v ? ei[E + e] : 0;
        b[k] = v ? (d[k] >> BKT_BITS) : NB;
        atomicAdd(&h[b[k]], 1);
    }
    __syncthreads();
    for (int i = tid; i < NB + 1; i += 256) {
        int c = h[i];
        base[i] = c ? atomicAdd(&bcur[i], c) : 0;
        h[i] = 0;
    }
    __syncthreads();
#pragma unroll
    for (int k = 0; k < 16; k++) {
        int r = atomicAdd(&h[b[k]], 1);
        pairs[base[b[k]] + r] = make_int2(s[k], d[k]);
    }
}

__global__ __launch_bounds__(256) void k_binB(const int2* __restrict__ pairs,
                                              const int* __restrict__ bb,
                                              int* __restrict__ csr,
                                              int* __restrict__ offs,
                                              float* __restrict__ dinv,
                                              int N, int NB, int E)
{
    __shared__ int hist[BKT_SIZE], start[BKT_SIZE], cur[BKT_SIZE];
    __shared__ int sc[BKT_SIZE];
    const int tid = threadIdx.x;
    const int b = blockIdx.x;
    const int d0 = b << BKT_BITS;
    const int pbg = bb[b], peg = bb[b + 1];

    if (tid < BKT_SIZE) { hist[tid] = 0; cur[tid] = 0; }
    __syncthreads();
    for (int i = pbg + tid; i < peg; i += 256)
        atomicAdd(&hist[pairs[i].y - d0], 1);
    __syncthreads();
    int own = (tid < BKT_SIZE) ? hist[tid] : 0;
    if (tid < BKT_SIZE) sc[tid] = own;
    __syncthreads();
    for (int st = 1; st < BKT_SIZE; st <<= 1) {
        int v = 0;
        bool act = (tid < BKT_SIZE) && (tid >= st);
        if (act) v = sc[tid - st];
        __syncthreads();
        if (act) sc[tid] += v;
        __syncthreads();
    }
    if (tid < BKT_SIZE) {
        int abs0 = pbg + (sc[tid] - own);
        start[tid] = abs0;
        int d = d0 + tid;
        if (d < N) {
            offs[d] = abs0;
            dinv[d] = rsqrtf((float)(own + 1));
        }
    }
    if (tid == 0 && b == NB - 1) offs[N] = E;
    __syncthreads();
    for (int i = pbg + tid; i < peg; i += 256) {
        int2 p = pairs[i];
        int ld = p.y - d0;
        int r = atomicAdd(&cur[ld], 1);
        csr[start[ld] + r] = p.x;
    }
}

// ---------------- GAT aggregation + fused bias/ELU/BN1 epilogue ------------
// hb pair t = channels (t, t+64); lane l owns (l, l+64); hA = l>>5.
// Epilogue applies f(v) = bn1w*elu(v+bgat)+bn1b so gemm2 reads pure bf16.
__global__ __launch_bounds__(256) void k_gat_aggr(
    const unsigned* __restrict__ hb, const float* __restrict__ aSg,
    const float* __restrict__ aDg, const int* __restrict__ offs,
    const int* __restrict__ csr,
    const float* __restrict__ bgat, const float* __restrict__ bn1w,
    const float* __restrict__ bn1b,
    unsigned short* __restrict__ raw1b, int N)
{
    __shared__ __align__(16) float s_u[4][64][4];   // (u0,u2,u1,u3)
    __shared__ int s_s[4][64];

    const int wid = threadIdx.x >> 6;
    const int lane = threadIdx.x & 63;
    const int n = blockIdx.x * 4 + wid;
    if (n >= N) return;

    const int beg = offs[n];
    const int cnt = offs[n + 1] - beg + 1;          // + self loop
    const float4 ad = *(const float4*)(aDg + (size_t)n * 4);
    const int hA = lane >> 5;
    const float* pu = &s_u[wid][0][2 * hA];
    const int* ps = &s_s[wid][0];

    float t0 = 0.f, t1 = 0.f, t2 = 0.f, t3 = 0.f;
    float accLo = 0.f, accHi = 0.f;

    for (int base = 0; base < cnt; base += 64) {
        int idx = base + lane;
        bool valid = idx < cnt;
        int src = n;
        if (valid && idx > 0) src = csr[beg + idx - 1];
        float u0 = 0.f, u1 = 0.f, u2 = 0.f, u3 = 0.f;
        if (valid) {
            float4 as = *(const float4*)(aSg + (size_t)src * 4);
            float l0 = as.x + ad.x; l0 = (l0 > 0.f) ? l0 : NEG_SLOPE * l0;
            float l1 = as.y + ad.y; l1 = (l1 > 0.f) ? l1 : NEG_SLOPE * l1;
            float l2 = as.z + ad.z; l2 = (l2 > 0.f) ? l2 : NEG_SLOPE * l2;
            float l3 = as.w + ad.w; l3 = (l3 > 0.f) ? l3 : NEG_SLOPE * l3;
            u0 = __expf(l0); u1 = __expf(l1); u2 = __expf(l2); u3 = __expf(l3);
        }
        t0 += u0; t1 += u1; t2 += u2; t3 += u3;
        s_s[wid][lane] = src;
        *(float4*)&s_u[wid][lane][0] = make_float4(u0, u2, u1, u3);

        int cc = min(64, cnt - base);
        int j = 0;
        for (; j + 8 <= cc; j += 8) {
            int sj[8]; float2 uj[8]; unsigned vv[8];
#pragma unroll
            for (int k = 0; k < 8; k++) sj[k] = ps[j + k];
#pragma unroll
            for (int k = 0; k < 8; k++) uj[k] = *(const float2*)&pu[(j + k) * 4];
#pragma unroll
            for (int k = 0; k < 8; k++) vv[k] = hb[sj[k] * 64 + lane];
#pragma unroll
            for (int k = 0; k < 8; k++) {
                float lo = __uint_as_float(vv[k] << 16);
                float hi = __uint_as_float(vv[k] & 0xffff0000u);
                accLo += uj[k].x * lo;
                accHi += uj[k].y * hi;
            }
        }
        for (; j < cc; j++) {
            int sj = ps[j];
            float2 uv = *(const float2*)&pu[j * 4];
            unsigned v = hb[sj * 64 + lane];
            accLo += uv.x * __uint_as_float(v << 16);
            accHi += uv.y * __uint_as_float(v & 0xffff0000u);
        }
    }
#pragma unroll
    for (int msk = 1; msk < 64; msk <<= 1) {
        t0 += __shfl_xor(t0, msk);
        t1 += __shfl_xor(t1, msk);
        t2 += __shfl_xor(t2, msk);
        t3 += __shfl_xor(t3, msk);
    }
    float sLo = (hA ? t1 : t0) + 1e-16f;
    float sHi = (hA ? t3 : t2) + 1e-16f;
    float o0 = accLo / sLo + bgat[lane];
    o0 = (o0 > 0.f) ? o0 : expm1f(o0);
    o0 = o0 * bn1w[lane] + bn1b[lane];
    float o1 = accHi / sHi + bgat[lane + 64];
    o1 = (o1 > 0.f) ? o1 : expm1f(o1);
    o1 = o1 * bn1w[lane + 64] + bn1b[lane + 64];
    raw1b[(size_t)n * 128 + lane]      = bf16_1(o0);
    raw1b[(size_t)n * 128 + 64 + lane] = bf16_1(o1);
}

// ---------------- GCN aggregation + fused BN2/ELU/gate/fc ------------------
__global__ __launch_bounds__(256) void k_gcn_aggr(
    const unsigned* __restrict__ h2b, const int* __restrict__ offs,
    const int* __restrict__ csr, const float* __restrict__ dinv,
    const float* __restrict__ bgcn,
    const float* __restrict__ bn2w, const float* __restrict__ bn2b,
    const float* __restrict__ wgate, const float* __restrict__ bgate,
    const float* __restrict__ wfc,
    float* __restrict__ gate, float* __restrict__ fcdot, int N)
{
    __shared__ int s_s[4][64];

    const int wid = threadIdx.x >> 6;
    const int lane = threadIdx.x & 63;
    const int n = blockIdx.x * 4 + wid;
    if (n >= N) return;

    const int beg = offs[n];
    const int cnt = offs[n + 1] - beg + 1;
    const float dn = dinv[n];
    const int* ps = &s_s[wid][0];

    float accLo = 0.f, accHi = 0.f;
    for (int base = 0; base < cnt; base += 64) {
        int idx = base + lane;
        int src = n;
        if (idx > 0 && idx < cnt) src = csr[beg + idx - 1];
        s_s[wid][lane] = src;

        int cc = min(64, cnt - base);
        int j = 0;
        for (; j + 8 <= cc; j += 8) {
            int sj[8]; unsigned vv[8];
#pragma unroll
            for (int k = 0; k < 8; k++) sj[k] = ps[j + k];
#pragma unroll
            for (int k = 0; k < 8; k++) vv[k] = h2b[sj[k] * 64 + lane];
#pragma unroll
            for (int k = 0; k < 8; k++) {
                accLo += __uint_as_float(vv[k] << 16);
                accHi += __uint_as_float(vv[k] & 0xffff0000u);
            }
        }
        for (; j < cc; j++) {
            unsigned v = h2b[ps[j] * 64 + lane];
            accLo += __uint_as_float(v << 16);
            accHi += __uint_as_float(v & 0xffff0000u);
        }
    }
    float v0 = dn * accLo + bgcn[lane];
    v0 = (v0 > 0.f) ? v0 : expm1f(v0);
    v0 = v0 * bn2w[lane] + bn2b[lane];
    float v1 = dn * accHi + bgcn[lane + 64];
    v1 = (v1 > 0.f) ? v1 : expm1f(v1);
    v1 = v1 * bn2w[lane + 64] + bn2b[lane + 64];

    float g = v0 * wgate[lane] + v1 * wgate[lane + 64];
    float f = v0 * wfc[lane]   + v1 * wfc[lane + 64];
#pragma unroll
    for (int msk = 1; msk < 64; msk <<= 1) {
        g += __shfl_xor(g, msk);
        f += __shfl_xor(f, msk);
    }
    if (lane == 0) { gate[n] = g + bgate[0]; fcdot[n] = f; }
}

// ---------------- pooling softmax over scalars: one block / graph ----------
__global__ __launch_bounds__(256) void k_pool(
    const float* __restrict__ gate, const float* __restrict__ fcdot,
    const int* __restrict__ batch, const float* __restrict__ bfc,
    float* __restrict__ out, int N)
{
    __shared__ float red[256];
    __shared__ int range[2];
    const int g = blockIdx.x;
    const int tid = threadIdx.x;
    if (tid < 2) range[tid] = lower_bound_i(batch, N, g + tid);
    __syncthreads();
    const int lo = range[0], hi = range[1];
    float se = 0.f, sf = 0.f;
    for (int i = lo + tid; i < hi; i += 256) {
        float e = __expf(gate[i]);
        se += e;
        sf += e * fcdot[i];
    }
    red[tid] = se; __syncthreads();
    for (int s = 128; s > 0; s >>= 1) {
        if (tid < s) red[tid] += red[tid + s];
        __syncthreads();
    }
    se = red[0]; __syncthreads();
    red[tid] = sf; __syncthreads();
    for (int s = 128; s > 0; s >>= 1) {
        if (tid < s) red[tid] += red[tid + s];
        __syncthreads();
    }
    sf = red[0];
    if (tid == 0) out[g] = sf / (se + 1e-16f) + bfc[0];
}

// ---------------------------------------------------------------------------
extern "C" void kernel_launch(void* const* d_in, const int* in_sizes, int n_in,
                              void* d_out, int out_size, void* d_ws, size_t ws_size,
                              hipStream_t stream) {
    const float* x     = (const float*)d_in[0];
    const int*   ei    = (const int*)d_in[1];
    const int*   batch = (const int*)d_in[2];
    const float* Wgat  = (const float*)d_in[3];
    const float* atts  = (const float*)d_in[4];
    const float* attd  = (const float*)d_in[5];
    const float* bgat  = (const float*)d_in[6];
    const float* bn1w  = (const float*)d_in[7];
    const float* bn1b  = (const float*)d_in[8];
    const float* Wgcn  = (const float*)d_in[9];
    const float* bgcn  = (const float*)d_in[10];
    const float* bn2w  = (const float*)d_in[11];
    const float* bn2b  = (const float*)d_in[12];
    const float* wgate = (const float*)d_in[13];
    const float* bgate = (const float*)d_in[14];
    const float* wfc   = (const float*)d_in[15];
    const float* bfc   = (const float*)d_in[16];
    float* out = (float*)d_out;

    const int N = in_sizes[0] / 128;
    const int E = in_sizes[1] / 2;
    const int NB = (N + BKT_SIZE - 1) / BKT_SIZE;
    const int NHB = (E + 2047) / 2048;             // hist blocks

    unsigned* hb  = (unsigned*)d_ws;               // bf16 h table   [N*64]
    unsigned* h2b = hb + (size_t)N * 64;           // bf16 h2s table [N*64]
    unsigned short* raw1b = (unsigned short*)(h2b + (size_t)N * 64); // [N*128]
    int2* pairs  = (int2*)raw1b;                   // aliased: pre-GAT only
    float* aS    = (float*)(raw1b + (size_t)N * 128); // [N*4]
    float* aD    = aS + (size_t)N * 4;             // [N*4]
    float* gate  = aD + (size_t)N * 4;             // [N]
    float* fcdot = gate + N;                       // [N]
    float* dinv  = fcdot + N;                      // [N]
    int* offs   = (int*)(dinv + N);                // [N+1]
    int* csr    = offs + (N + 1);                  // [E]
    int* bcount = csr + E;                         // [NB+1]
    int* bb     = bcount + (NB + 1);               // [NB+1]
    int* bcur   = bb + (NB + 1);                   // [NB+1]
    unsigned short* Wf1 = (unsigned short*)(bcur + (NB + 1)); // [9*4*64*8]
    unsigned short* Wf2 = Wf1 + 9 * 4 * 64 * 8;               // [8*4*64*8]

    hipMemsetAsync(bcount, 0, (size_t)(NB + 1) * sizeof(int), stream);

    const int gemm_blocks = (N + 63) / 64;
    const int aggr_blocks = (N + 3) / 4;

    k_front<<<NHB + 2, 256, 0, stream>>>(Wgat, atts, attd, Wgcn, Wf1, Wf2,
                                         ei + E, bcount, E, NB);
    k_gemm_mfma<0><<<gemm_blocks, 256, 0, stream>>>(x, Wf1, hb, N,
                                                    nullptr, aS, aD);
    k_bscan<<<1, 512, 0, stream>>>(bcount, bb, bcur, NB);
    k_binA<<<(E + CHUNK_A - 1) / CHUNK_A, 256, 0, stream>>>(ei, bcur, pairs, E, NB);
    k_binB<<<NB, 256, 0, stream>>>(pairs, bb, csr, offs, dinv, N, NB, E);
    k_gat_aggr<<<aggr_blocks, 256, 0, stream>>>(hb, aS, aD, offs, csr,
                                                bgat, bn1w, bn1b, raw1b, N);
    k_gemm_mfma<1><<<gemm_blocks, 256, 0, stream>>>(raw1b, Wf2, h2b, N,
                                                    dinv, nullptr, nullptr);
    k_gcn_aggr<<<aggr_blocks, 256, 0, stream>>>(h2b, offs, csr, dinv, bgcn,
                                                bn2w, bn2b, wgate, bgate, wfc,
                                                gate, fcdot, N);
    k_pool<<<64, 256, 0, stream>>>(gate, fcdot, batch, bfc, out, N);
}

// Round 12
// 266.864 us; speedup vs baseline: 1.0144x; 1.0144x over previous
//
#include <hip/hip_runtime.h>
#include <math.h>

// GoBERT: GATConv(4x32) -> BN -> GCNConv(128) -> BN -> GlobalAttention -> FC
// Round 12: de-serialize the CSR path. k_bscan deleted (binA/binB redo the
// 512-entry bucket scan locally in LDS - intra-block, safe); gemm1 and binA
// fused into one dispatch via block-role split (they share no dependency:
// both only need k_front's outputs). 10 dispatches -> 8.

#define NEG_SLOPE 0.2f
#define BKT_BITS 7
#define BKT_SIZE 128
#define CHUNK_A 4096

typedef __attribute__((ext_vector_type(8))) short short8v;
typedef __attribute__((ext_vector_type(4))) float floatx4;

__device__ __forceinline__ int lower_bound_i(const int* a, int n, int key) {
    int lo = 0, hi = n;
    while (lo < hi) {
        int mid = (lo + hi) >> 1;
        if (a[mid] < key) lo = mid + 1; else hi = mid;
    }
    return lo;
}

__device__ __forceinline__ unsigned pack_bf16(float lo, float hi) {
    unsigned ua = __float_as_uint(lo);
    unsigned ub = __float_as_uint(hi);
    ua = ua + 0x7fffu + ((ua >> 16) & 1u);
    ub = ub + 0x7fffu + ((ub >> 16) & 1u);
    return (ua >> 16) | (ub & 0xffff0000u);
}

__device__ __forceinline__ unsigned short bf16_1(float v) {
    unsigned u = __float_as_uint(v);
    u = u + 0x7fffu + ((u >> 16) & 1u);
    return (unsigned short)(u >> 16);
}

// ---------------- front: fragment-ordered weights + bucket hist ------------
// Wf[(ct*4+ks)*512 + lane*8 + j] = W^T[col=ct*16+(lane&15)][k=ks*32+(lane>>4)*8+j]
__global__ __launch_bounds__(256) void k_front(
    const float* __restrict__ W1, const float* __restrict__ atts,
    const float* __restrict__ attd, const float* __restrict__ W2,
    unsigned short* __restrict__ Wf1, unsigned short* __restrict__ Wf2,
    const int* __restrict__ dst, int* __restrict__ bcount, int E, int NB)
{
    const int b = blockIdx.x;
    if (b < 2) {
        const int NCT = b ? 8 : 9;
        const float* W = b ? W2 : W1;
        unsigned short* Wf = b ? Wf2 : Wf1;
        const int lim = NCT * 4 * 64 * 8;
        for (int idx = threadIdx.x; idx < lim; idx += 256) {
            int j = idx & 7;
            int lane = (idx >> 3) & 63;
            int frag = idx >> 9;            // ct*4 + ks
            int ct = frag >> 2, ks = frag & 3;
            int quad = lane >> 4, l16 = lane & 15;
            int k = ks * 32 + quad * 8 + j;
            float v;
            if (ct < 8) {
                v = W[k * 128 + ct * 16 + l16];
            } else if (l16 < 4) {
                float s = 0.f;
                for (int c = 0; c < 32; c++) s += W1[k * 128 + l16 * 32 + c] * atts[l16 * 32 + c];
                v = s;
            } else if (l16 < 8) {
                int h = l16 - 4;
                float s = 0.f;
                for (int c = 0; c < 32; c++) s += W1[k * 128 + h * 32 + c] * attd[h * 32 + c];
                v = s;
            } else v = 0.f;
            Wf[idx] = bf16_1(v);
        }
    } else {
        __shared__ int h[512];
        const int tid = threadIdx.x;
        for (int i = tid; i < 512; i += 256) h[i] = 0;
        __syncthreads();
        int base = (b - 2) * 2048;
#pragma unroll
        for (int k = 0; k < 8; k++) {
            int e = base + k * 256 + tid;
            if (e < E) atomicAdd(&h[dst[e] >> BKT_BITS], 1);
        }
        __syncthreads();
        for (int i = tid; i < NB; i += 256) {
            int c = h[i];
            if (c) atomicAdd(&bcount[i], c);
        }
    }
}

// ---------------- fused: LDS-free MFMA GEMM-1 (blocks < nGemm) -------------
//                + binA bucket scatter (blocks >= nGemm, local scan) --------
__global__ __launch_bounds__(256) void k_gemm1_binA(
    const float* __restrict__ x, const unsigned short* __restrict__ Wf1,
    unsigned* __restrict__ hb, float* __restrict__ aS, float* __restrict__ aD,
    const int* __restrict__ ei, const int* __restrict__ bcount,
    int* __restrict__ bcur, int2* __restrict__ pairs,
    int N, int E, int NB, int nGemm)
{
    const int tid = threadIdx.x;
    if ((int)blockIdx.x < nGemm) {
        // ---- GEMM-1: 64 rows/block, NCT=9, zero LDS ----
        const int wv = tid >> 6, lane = tid & 63;
        const int quad = lane >> 4, l16 = lane & 15;
        const int n0 = blockIdx.x * 64;
        const int arow = n0 + wv * 16 + l16;
        const bool rowok = arow < N;

        floatx4 acc[9];
#pragma unroll
        for (int ct = 0; ct < 9; ct++) acc[ct] = (floatx4){0.f, 0.f, 0.f, 0.f};
        union AV { unsigned u[4]; short8v v; };
#pragma unroll
        for (int ks = 0; ks < 4; ks++) {
            AV a;
            a.u[0] = a.u[1] = a.u[2] = a.u[3] = 0u;
            if (rowok) {
                const float* p = x + (size_t)arow * 128 + ks * 32 + quad * 8;
                float4 va = *(const float4*)(p);
                float4 vb = *(const float4*)(p + 4);
                a.u[0] = pack_bf16(va.x, va.y);
                a.u[1] = pack_bf16(va.z, va.w);
                a.u[2] = pack_bf16(vb.x, vb.y);
                a.u[3] = pack_bf16(vb.z, vb.w);
            }
#pragma unroll
            for (int ct = 0; ct < 9; ct++) {
                short8v bv = *(const short8v*)(Wf1 + ((ct * 4 + ks) << 9) + lane * 8);
                acc[ct] = __builtin_amdgcn_mfma_f32_16x16x32_bf16(a.v, bv, acc[ct], 0, 0, 0);
            }
        }
#pragma unroll
        for (int r = 0; r < 4; r++) {
            int n = n0 + wv * 16 + quad * 4 + r;
            if (n >= N) continue;
#pragma unroll
            for (int ct = 0; ct < 4; ct++) {
                hb[(size_t)n * 64 + ct * 16 + l16] =
                    pack_bf16(acc[ct][r], acc[ct + 4][r]);
            }
            float e = acc[8][r];
            if (l16 < 4) aS[(size_t)n * 4 + l16] = e;
            else if (l16 < 8) aD[(size_t)n * 4 + (l16 - 4)] = e;
        }
    } else {
        // ---- binA chunk: local scan of bcount -> bucket bases, scatter ----
        __shared__ int sc[512];
        __shared__ int bbloc[512];
        __shared__ int h[512];
        __shared__ int base[512];
        const int chunk = blockIdx.x - nGemm;

        // local 512-entry exclusive scan of bcount (2 elems/thread)
        const int p0 = tid, p1 = tid + 256;
        int own0 = (p0 < NB) ? bcount[p0] : 0;
        int own1 = (p1 < NB) ? bcount[p1] : 0;
        sc[p0] = own0; sc[p1] = own1;
        __syncthreads();
        for (int st = 1; st < 512; st <<= 1) {
            int r0 = (p0 >= st) ? sc[p0 - st] : 0;
            int r1 = (p1 >= st) ? sc[p1 - st] : 0;
            __syncthreads();
            sc[p0] += r0; sc[p1] += r1;
            __syncthreads();
        }
        bbloc[p0] = sc[p0] - own0;
        bbloc[p1] = sc[p1] - own1;
        h[p0] = 0; h[p1] = 0;
        __syncthreads();

        const int c0 = chunk * CHUNK_A;
        int s[16], d[16], b[16];
#pragma unroll
        for (int k = 0; k < 16; k++) {
            int e = c0 + k * 256 + tid;
            bool v = e < E;
            s[k] = v ? ei[e] : 0;
            d[k] = v ? ei[E + e] : 0;
            b[k] = v ? (d[k] >> BKT_BITS) : (NB < 511 ? 511 : NB);  // sentinel
            atomicAdd(&h[b[k]], 1);
        }
        __syncthreads();
        for (int i = tid; i < 512; i += 256) {
            int c = h[i];
            base[i] = (c && i < NB) ? (bbloc[i] + atomicAdd(&bcur[i], c)) : 0;
            h[i] = 0;
        }
        __syncthreads();
#pragma unroll
        for (int k = 0; k < 16; k++) {
            int r = atomicAdd(&h[b[k]], 1);
            if (b[k] < NB) pairs[base[b[k]] + r] = make_int2(s[k], d[k]);
        }
    }
}

// ---------------- binB: bucket -> CSR (local scan for bucket offsets) ------
__global__ __launch_bounds__(256) void k_binB(const int2* __restrict__ pairs,
                                              const int* __restrict__ bcount,
                                              int* __restrict__ csr,
                                              int* __restrict__ offs,
                                              float* __restrict__ dinv,
                                              int N, int NB, int E)
{
    __shared__ int scg[512];
    __shared__ int hist[BKT_SIZE], start[BKT_SIZE], cur[BKT_SIZE];
    __shared__ int sc[BKT_SIZE];
    const int tid = threadIdx.x;
    const int b = blockIdx.x;
    const int d0 = b << BKT_BITS;

    // local 512-entry scan of bcount to get this bucket's window
    const int p0 = tid, p1 = tid + 256;
    int own0 = (p0 < NB) ? bcount[p0] : 0;
    int own1 = (p1 < NB) ? bcount[p1] : 0;
    scg[p0] = own0; scg[p1] = own1;
    __syncthreads();
    for (int st = 1; st < 512; st <<= 1) {
        int r0 = (p0 >= st) ? scg[p0 - st] : 0;
        int r1 = (p1 >= st) ? scg[p1 - st] : 0;
        __syncthreads();
        scg[p0] += r0; scg[p1] += r1;
        __syncthreads();
    }
    const int peg = scg[b];                    // inclusive sum through b
    const int pbg = peg - ((b < NB) ? bcount[b] : 0);

    if (tid < BKT_SIZE) { hist[tid] = 0; cur[tid] = 0; }
    __syncthreads();
    for (int i = pbg + tid; i < peg; i += 256)
        atomicAdd(&hist[pairs[i].y - d0], 1);
    __syncthreads();
    int own = (tid < BKT_SIZE) ? hist[tid] : 0;
    if (tid < BKT_SIZE) sc[tid] = own;
    __syncthreads();
    for (int st = 1; st < BKT_SIZE; st <<= 1) {
        int v = 0;
        bool act = (tid < BKT_SIZE) && (tid >= st);
        if (act) v = sc[tid - st];
        __syncthreads();
        if (act) sc[tid] += v;
        __syncthreads();
    }
    if (tid < BKT_SIZE) {
        int abs0 = pbg + (sc[tid] - own);
        start[tid] = abs0;
        int d = d0 + tid;
        if (d < N) {
            offs[d] = abs0;
            dinv[d] = rsqrtf((float)(own + 1));
        }
    }
    if (tid == 0 && b == NB - 1) offs[N] = E;
    __syncthreads();
    for (int i = pbg + tid; i < peg; i += 256) {
        int2 p = pairs[i];
        int ld = p.y - d0;
        int r = atomicAdd(&cur[ld], 1);
        csr[start[ld] + r] = p.x;
    }
}

// ---------------- GAT aggregation + fused bias/ELU/BN1 epilogue ------------
__global__ __launch_bounds__(256) void k_gat_aggr(
    const unsigned* __restrict__ hb, const float* __restrict__ aSg,
    const float* __restrict__ aDg, const int* __restrict__ offs,
    const int* __restrict__ csr,
    const float* __restrict__ bgat, const float* __restrict__ bn1w,
    const float* __restrict__ bn1b,
    unsigned short* __restrict__ raw1b, int N)
{
    __shared__ __align__(16) float s_u[4][64][4];   // (u0,u2,u1,u3)
    __shared__ int s_s[4][64];

    const int wid = threadIdx.x >> 6;
    const int lane = threadIdx.x & 63;
    const int n = blockIdx.x * 4 + wid;
    if (n >= N) return;

    const int beg = offs[n];
    const int cnt = offs[n + 1] - beg + 1;          // + self loop
    const float4 ad = *(const float4*)(aDg + (size_t)n * 4);
    const int hA = lane >> 5;
    const float* pu = &s_u[wid][0][2 * hA];
    const int* ps = &s_s[wid][0];

    float t0 = 0.f, t1 = 0.f, t2 = 0.f, t3 = 0.f;
    float accLo = 0.f, accHi = 0.f;

    for (int base = 0; base < cnt; base += 64) {
        int idx = base + lane;
        bool valid = idx < cnt;
        int src = n;
        if (valid && idx > 0) src = csr[beg + idx - 1];
        float u0 = 0.f, u1 = 0.f, u2 = 0.f, u3 = 0.f;
        if (valid) {
            float4 as = *(const float4*)(aSg + (size_t)src * 4);
            float l0 = as.x + ad.x; l0 = (l0 > 0.f) ? l0 : NEG_SLOPE * l0;
            float l1 = as.y + ad.y; l1 = (l1 > 0.f) ? l1 : NEG_SLOPE * l1;
            float l2 = as.z + ad.z; l2 = (l2 > 0.f) ? l2 : NEG_SLOPE * l2;
            float l3 = as.w + ad.w; l3 = (l3 > 0.f) ? l3 : NEG_SLOPE * l3;
            u0 = __expf(l0); u1 = __expf(l1); u2 = __expf(l2); u3 = __expf(l3);
        }
        t0 += u0; t1 += u1; t2 += u2; t3 += u3;
        s_s[wid][lane] = src;
        *(float4*)&s_u[wid][lane][0] = make_float4(u0, u2, u1, u3);

        int cc = min(64, cnt - base);
        int j = 0;
        for (; j + 8 <= cc; j += 8) {
            int sj[8]; float2 uj[8]; unsigned vv[8];
#pragma unroll
            for (int k = 0; k < 8; k++) sj[k] = ps[j + k];
#pragma unroll
            for (int k = 0; k < 8; k++) uj[k] = *(const float2*)&pu[(j + k) * 4];
#pragma unroll
            for (int k = 0; k < 8; k++) vv[k] = hb[sj[k] * 64 + lane];
#pragma unroll
            for (int k = 0; k < 8; k++) {
                float lo = __uint_as_float(vv[k] << 16);
                float hi = __uint_as_float(vv[k] & 0xffff0000u);
                accLo += uj[k].x * lo;
                accHi += uj[k].y * hi;
            }
        }
        for (; j < cc; j++) {
            int sj = ps[j];
            float2 uv = *(const float2*)&pu[j * 4];
            unsigned v = hb[sj * 64 + lane];
            accLo += uv.x * __uint_as_float(v << 16);
            accHi += uv.y * __uint_as_float(v & 0xffff0000u);
        }
    }
#pragma unroll
    for (int msk = 1; msk < 64; msk <<= 1) {
        t0 += __shfl_xor(t0, msk);
        t1 += __shfl_xor(t1, msk);
        t2 += __shfl_xor(t2, msk);
        t3 += __shfl_xor(t3, msk);
    }
    float sLo = (hA ? t1 : t0) + 1e-16f;
    float sHi = (hA ? t3 : t2) + 1e-16f;
    float o0 = accLo / sLo + bgat[lane];
    o0 = (o0 > 0.f) ? o0 : expm1f(o0);
    o0 = o0 * bn1w[lane] + bn1b[lane];
    float o1 = accHi / sHi + bgat[lane + 64];
    o1 = (o1 > 0.f) ? o1 : expm1f(o1);
    o1 = o1 * bn1w[lane + 64] + bn1b[lane + 64];
    raw1b[(size_t)n * 128 + lane]      = bf16_1(o0);
    raw1b[(size_t)n * 128 + 64 + lane] = bf16_1(o1);
}

// ---------------- LDS-free MFMA GEMM-2: bf16 A, NCT=8 ----------------------
__global__ __launch_bounds__(256) void k_gemm2(
    const unsigned short* __restrict__ A, const unsigned short* __restrict__ Wf,
    unsigned* __restrict__ Cb, int N, const float* __restrict__ dinv)
{
    const int tid = threadIdx.x;
    const int wv = tid >> 6, lane = tid & 63;
    const int quad = lane >> 4, l16 = lane & 15;
    const int n0 = blockIdx.x * 64;
    const int arow = n0 + wv * 16 + l16;
    const bool rowok = arow < N;

    floatx4 acc[8];
#pragma unroll
    for (int ct = 0; ct < 8; ct++) acc[ct] = (floatx4){0.f, 0.f, 0.f, 0.f};
    union AV { unsigned u[4]; short8v v; };
#pragma unroll
    for (int ks = 0; ks < 4; ks++) {
        AV a;
        a.u[0] = a.u[1] = a.u[2] = a.u[3] = 0u;
        if (rowok) a.v = *(const short8v*)(A + (size_t)arow * 128 + ks * 32 + quad * 8);
#pragma unroll
        for (int ct = 0; ct < 8; ct++) {
            short8v bv = *(const short8v*)(Wf + ((ct * 4 + ks) << 9) + lane * 8);
            acc[ct] = __builtin_amdgcn_mfma_f32_16x16x32_bf16(a.v, bv, acc[ct], 0, 0, 0);
        }
    }
#pragma unroll
    for (int r = 0; r < 4; r++) {
        int n = n0 + wv * 16 + quad * 4 + r;
        if (n >= N) continue;
        float s = dinv[n];
#pragma unroll
        for (int ct = 0; ct < 4; ct++) {
            Cb[(size_t)n * 64 + ct * 16 + l16] =
                pack_bf16(acc[ct][r] * s, acc[ct + 4][r] * s);
        }
    }
}

// ---------------- GCN aggregation + fused BN2/ELU/gate/fc ------------------
__global__ __launch_bounds__(256) void k_gcn_aggr(
    const unsigned* __restrict__ h2b, const int* __restrict__ offs,
    const int* __restrict__ csr, const float* __restrict__ dinv,
    const float* __restrict__ bgcn,
    const float* __restrict__ bn2w, const float* __restrict__ bn2b,
    const float* __restrict__ wgate, const float* __restrict__ bgate,
    const float* __restrict__ wfc,
    float* __restrict__ gate, float* __restrict__ fcdot, int N)
{
    __shared__ int s_s[4][64];

    const int wid = threadIdx.x >> 6;
    const int lane = threadIdx.x & 63;
    const int n = blockIdx.x * 4 + wid;
    if (n >= N) return;

    const int beg = offs[n];
    const int cnt = offs[n + 1] - beg + 1;
    const float dn = dinv[n];
    const int* ps = &s_s[wid][0];

    float accLo = 0.f, accHi = 0.f;
    for (int base = 0; base < cnt; base += 64) {
        int idx = base + lane;
        int src = n;
        if (idx > 0 && idx < cnt) src = csr[beg + idx - 1];
        s_s[wid][lane] = src;

        int cc = min(64, cnt - base);
        int j = 0;
        for (; j + 8 <= cc; j += 8) {
            int sj[8]; unsigned vv[8];
#pragma unroll
            for (int k = 0; k < 8; k++) sj[k] = ps[j + k];
#pragma unroll
            for (int k = 0; k < 8; k++) vv[k] = h2b[sj[k] * 64 + lane];
#pragma unroll
            for (int k = 0; k < 8; k++) {
                accLo += __uint_as_float(vv[k] << 16);
                accHi += __uint_as_float(vv[k] & 0xffff0000u);
            }
        }
        for (; j < cc; j++) {
            unsigned v = h2b[ps[j] * 64 + lane];
            accLo += __uint_as_float(v << 16);
            accHi += __uint_as_float(v & 0xffff0000u);
        }
    }
    float v0 = dn * accLo + bgcn[lane];
    v0 = (v0 > 0.f) ? v0 : expm1f(v0);
    v0 = v0 * bn2w[lane] + bn2b[lane];
    float v1 = dn * accHi + bgcn[lane + 64];
    v1 = (v1 > 0.f) ? v1 : expm1f(v1);
    v1 = v1 * bn2w[lane + 64] + bn2b[lane + 64];

    float g = v0 * wgate[lane] + v1 * wgate[lane + 64];
    float f = v0 * wfc[lane]   + v1 * wfc[lane + 64];
#pragma unroll
    for (int msk = 1; msk < 64; msk <<= 1) {
        g += __shfl_xor(g, msk);
        f += __shfl_xor(f, msk);
    }
    if (lane == 0) { gate[n] = g + bgate[0]; fcdot[n] = f; }
}

// ---------------- pooling softmax over scalars: one block / graph ----------
__global__ __launch_bounds__(256) void k_pool(
    const float* __restrict__ gate, const float* __restrict__ fcdot,
    const int* __restrict__ batch, const float* __restrict__ bfc,
    float* __restrict__ out, int N)
{
    __shared__ float red[256];
    __shared__ int range[2];
    const int g = blockIdx.x;
    const int tid = threadIdx.x;
    if (tid < 2) range[tid] = lower_bound_i(batch, N, g + tid);
    __syncthreads();
    const int lo = range[0], hi = range[1];
    float se = 0.f, sf = 0.f;
    for (int i = lo + tid; i < hi; i += 256) {
        float e = __expf(gate[i]);
        se += e;
        sf += e * fcdot[i];
    }
    red[tid] = se; __syncthreads();
    for (int s = 128; s > 0; s >>= 1) {
        if (tid < s) red[tid] += red[tid + s];
        __syncthreads();
    }
    se = red[0]; __syncthreads();
    red[tid] = sf; __syncthreads();
    for (int s = 128; s > 0; s >>= 1) {
        if (tid < s) red[tid] += red[tid + s];
        __syncthreads();
    }
    sf = red[0];
    if (tid == 0) out[g] = sf / (se + 1e-16f) + bfc[0];
}

// ---------------------------------------------------------------------------
extern "C" void kernel_launch(void* const* d_in, const int* in_sizes, int n_in,
                              void* d_out, int out_size, void* d_ws, size_t ws_size,
                              hipStream_t stream) {
    const float* x     = (const float*)d_in[0];
    const int*   ei    = (const int*)d_in[1];
    const int*   batch = (const int*)d_in[2];
    const float* Wgat  = (const float*)d_in[3];
    const float* atts  = (const float*)d_in[4];
    const float* attd  = (const float*)d_in[5];
    const float* bgat  = (const float*)d_in[6];
    const float* bn1w  = (const float*)d_in[7];
    const float* bn1b  = (const float*)d_in[8];
    const float* Wgcn  = (const float*)d_in[9];
    const float* bgcn  = (const float*)d_in[10];
    const float* bn2w  = (const float*)d_in[11];
    const float* bn2b  = (const float*)d_in[12];
    const float* wgate = (const float*)d_in[13];
    const float* bgate = (const float*)d_in[14];
    const float* wfc   = (const float*)d_in[15];
    const float* bfc   = (const float*)d_in[16];
    float* out = (float*)d_out;

    const int N = in_sizes[0] / 128;
    const int E = in_sizes[1] / 2;
    const int NB = (N + BKT_SIZE - 1) / BKT_SIZE;
    const int NHB = (E + 2047) / 2048;             // hist blocks
    const int NCH = (E + CHUNK_A - 1) / CHUNK_A;   // binA chunks

    unsigned* hb  = (unsigned*)d_ws;               // bf16 h table   [N*64]
    unsigned* h2b = hb + (size_t)N * 64;           // bf16 h2s table [N*64]
    unsigned short* raw1b = (unsigned short*)(h2b + (size_t)N * 64); // [N*128]
    int2* pairs  = (int2*)raw1b;                   // aliased: pre-GAT only
    float* aS    = (float*)(raw1b + (size_t)N * 128); // [N*4]
    float* aD    = aS + (size_t)N * 4;             // [N*4]
    float* gate  = aD + (size_t)N * 4;             // [N]
    float* fcdot = gate + N;                       // [N]
    float* dinv  = fcdot + N;                      // [N]
    int* offs   = (int*)(dinv + N);                // [N+1]
    int* csr    = offs + (N + 1);                  // [E]
    int* bcount = csr + E;                         // [NB+1]
    int* bcur   = bcount + (NB + 1);               // [NB+1]
    unsigned short* Wf1 = (unsigned short*)(bcur + (NB + 1)); // [9*4*64*8]
    unsigned short* Wf2 = Wf1 + 9 * 4 * 64 * 8;               // [8*4*64*8]

    // zero bcount AND bcur in one memset (contiguous)
    hipMemsetAsync(bcount, 0, (size_t)(2 * (NB + 1)) * sizeof(int), stream);

    const int gemm_blocks = (N + 63) / 64;
    const int aggr_blocks = (N + 3) / 4;

    k_front<<<NHB + 2, 256, 0, stream>>>(Wgat, atts, attd, Wgcn, Wf1, Wf2,
                                         ei + E, bcount, E, NB);
    k_gemm1_binA<<<gemm_blocks + NCH, 256, 0, stream>>>(
        x, Wf1, hb, aS, aD, ei, bcount, bcur, pairs, N, E, NB, gemm_blocks);
    k_binB<<<NB, 256, 0, stream>>>(pairs, bcount, csr, offs, dinv, N, NB, E);
    k_gat_aggr<<<aggr_blocks, 256, 0, stream>>>(hb, aS, aD, offs, csr,
                                                bgat, bn1w, bn1b, raw1b, N);
    k_gemm2<<<gemm_blocks, 256, 0, stream>>>(raw1b, Wf2, h2b, N, dinv);
    k_gcn_aggr<<<aggr_blocks, 256, 0, stream>>>(h2b, offs, csr, dinv, bgcn,
                                                bn2w, bn2b, wgate, bgate, wfc,
                                                gate, fcdot, N);
    k_pool<<<64, 256, 0, stream>>>(gate, fcdot, batch, bfc, out, N);
}